// Round 3
// baseline (1028.877 us; speedup 1.0000x reference)
//
#include <hip/hip_runtime.h>
#include <hip/hip_cooperative_groups.h>
#include <math.h>

namespace cg = cooperative_groups;

// CRF-RNN mean-field, MI355X.  seg:[4][21][4096] f32, W:[4][4096][4096] f32, wc:[21][21] f32.
// qVals_{t+1}[b,d,m] = seg[b,d,m] - sum_e wc[d,e] * (sum_n Q_t[b,e,n] * W[b,m,n]) / rs[b,m],
//   rs = rowsum(W).  Round-6: ONE persistent cooperative kernel.
//   * W is read ONCE (256 MiB, the irreducible HBM floor), converted to fp8 e4m3
//     directly into REGISTERS in exact MFMA A-fragment layout (128 VGPR/lane:
//     64 longs = 2 rows x 32 k-slabs x 8 bytes).  D is never materialized in
//     global: saves the 64 MiB write + 5x64 MiB re-read of rounds 2-5.
//   * rowsum normalization deferred to the epilogue (divide the compat-mixed
//     GEMM result by rs[m]) -- algebraically identical, enables single-pass
//     streaming conversion.  inv_rs kept in LDS (persists across iterations).
//   * 5 iterations inside the kernel, separated by grid.sync() (Q ping-pong
//     ws <-> d_out).  Per iteration only Q is staged: per-wave-PRIVATE
//     double-buffered LDS chunks via global_load_lds width=16 with counted
//     vmcnt(8) -- zero barriers in the k-loop (A comes from registers).
//   * Fragment geometry, XOR swizzle ((cls&7)<<4 on global source + LDS read),
//     epilogue (cross-wave K-split reduce via LDS Cf, compat mix, seg-subtract,
//     fused next-softmax -> fp8 Q) all carried over from the round-2 kernel.
//   * fp8 conversion via HW v_cvt_pk_fp8_f32 (OCP e4m3 on gfx950), software
//     fallback if builtin unavailable.
// Fallback: if hipLaunchCooperativeKernel is rejected, run the round-2
// multi-kernel path (kept verbatim below); if ws too small, fp32 fallback.

#define DC 21
#define DCP 32
#define NN 4096
#define BS 4

typedef unsigned int u32;
typedef unsigned short u16;
typedef unsigned char u8;
typedef float f4v __attribute__((ext_vector_type(4)));

typedef __attribute__((address_space(1))) const unsigned int as1_u32;
typedef __attribute__((address_space(3))) unsigned int as3_u32;

#define WAITVM(n) asm volatile("s_waitcnt vmcnt(" #n ")" ::: "memory")

// f32 -> fp8 e4m3fn (RNE), nonneg inputs only, values <= ~4 (software path).
__device__ __forceinline__ u8 f2e4(float f) {
    if (!(f >= 0.015625f)) {                       // subnormal region (< 2^-6)
        int q = __float2int_rn(f * 512.0f);        // grid 2^-9; q in 0..8
        return (u8)q;                              // q==8 -> exp1 mant0 = 2^-6 (ok)
    }
    u32 b = __float_as_uint(f);
    b += 0x7FFFFu + ((b >> 20) & 1u);              // RNE into 3-bit mantissa
    return (u8)(((((b >> 23) & 0xFFu) - 120u) << 3) | ((b >> 20) & 7u));
}

__device__ __forceinline__ u32 cvtpk4(float a, float b, float c, float d) {
#if __has_builtin(__builtin_amdgcn_cvt_pk_fp8_f32)
    u32 v = __builtin_amdgcn_cvt_pk_fp8_f32(a, b, 0u, false);
    v = __builtin_amdgcn_cvt_pk_fp8_f32(c, d, v, true);
    return v;
#else
    return (u32)f2e4(a) | ((u32)f2e4(b) << 8) |
           ((u32)f2e4(c) << 16) | ((u32)f2e4(d) << 24);
#endif
}

__device__ __forceinline__ u8 cvt1(float a) {
#if __has_builtin(__builtin_amdgcn_cvt_pk_fp8_f32)
    return (u8)(__builtin_amdgcn_cvt_pk_fp8_f32(a, 0.f, 0u, false) & 0xFFu);
#else
    return f2e4(a);
#endif
}

__device__ __forceinline__ void qnextw(u8* q, int b, int d, int m, u8 v) {
    q[((size_t)b * DCP + d) * NN + m] = v;
}

// ==================== persistent cooperative kernel ====================
__global__ __launch_bounds__(256, 2) void fused_k(const float* __restrict__ seg,
                                                  const float* __restrict__ W,
                                                  const float* __restrict__ wc,
                                                  u8* __restrict__ q0,
                                                  u8* __restrict__ q1,
                                                  float* __restrict__ out) {
    // per-wave-private Q staging: [wave][dbuf][8 KiB]  (64 KiB total)
    __shared__ __align__(16) char bstage[4][2][8192];
    __shared__ float wcs[DC * DC];
    __shared__ float inv_rs[32];
    __shared__ float rs_part[4][32];
    // Cf (16 KiB) aliases wave-0's staging region; barrier-protected.
    float (*Cf)[2][16][DCP] = (float (*)[2][16][DCP])&bstage[0][0][0];

    cg::grid_group grid = cg::this_grid();

    const int tid = threadIdx.x;
    const int w   = tid >> 6;            // wave id = k-quarter owner
    const int l   = tid & 63;
    const int b   = blockIdx.x >> 7;     // batch
    const int m0  = (blockIdx.x & 127) * 32;

    const int r    = l & 15;             // A row (within 16-row tile) / B class
    const int q4   = l >> 4;             // k-run offset q4*8 within a K=32 step
    const int drow = l >> 4;             // DMA: row-within-instr
    const int dinn = (l & 15) * 16;      // DMA: inner byte offset

    for (int i = tid; i < DC * DC; i += 256) wcs[i] = wc[i];   // UNscaled

    // ---- phase 0: initial softmax share (32 columns per block, lanes 0..31) ----
    if (tid < 32) {
        const int col = blockIdx.x * 32 + tid;     // 0..16383
        const int bb = col >> 12, n = col & 4095;
        const float* xb = seg + (size_t)bb * DC * NN + n;
        float v[DC];
        float mx = -1e30f;
#pragma unroll
        for (int d = 0; d < DC; ++d) { v[d] = xb[(size_t)d * NN]; mx = fmaxf(mx, v[d]); }
        float s = 0.f;
#pragma unroll
        for (int d = 0; d < DC; ++d) { v[d] = __expf(v[d] - mx); s += v[d]; }
        const float inv = 1.f / s;
        u8* qb = q0 + (size_t)bb * DCP * NN + n;
#pragma unroll
        for (int d = 0; d < DC; ++d) qb[(size_t)d * NN] = cvt1(v[d] * inv);
    }

    // ---- phase 1: stream W quarter -> fp8 A-frags in registers + rowsums ----
    // dreg[row2*32 + ks] = fp8x8 of W[m0 + row2*16 + r][w*1024 + ks*32 + q4*8 ..+8]
    long dreg[64];
    const float* Wb = W + ((size_t)(b * NN + m0)) * NN + w * 1024 + q4 * 8;
    float s0 = 0.f, s1 = 0.f;
#pragma unroll
    for (int row2 = 0; row2 < 2; ++row2) {
        const float* Wr = Wb + (size_t)(row2 * 16 + r) * NN;
#pragma unroll
        for (int ks = 0; ks < 32; ++ks) {
            float4 va = *(const float4*)(Wr + ks * 32);
            float4 vb = *(const float4*)(Wr + ks * 32 + 4);
            float sm = ((va.x + va.y) + (va.z + va.w)) +
                       ((vb.x + vb.y) + (vb.z + vb.w));
            if (row2 == 0) s0 += sm; else s1 += sm;
            u32 lo = cvtpk4(va.x, va.y, va.z, va.w);
            u32 hi = cvtpk4(vb.x, vb.y, vb.z, vb.w);
            dreg[row2 * 32 + ks] = (long)(((unsigned long)hi << 32) | (unsigned long)lo);
        }
    }
    // reduce quarter-sums across q4 lanes (stride 16, same r)
    s0 += __shfl_xor(s0, 16); s0 += __shfl_xor(s0, 32);
    s1 += __shfl_xor(s1, 16); s1 += __shfl_xor(s1, 32);
    if (l < 16) { rs_part[w][r] = s0; rs_part[w][16 + r] = s1; }
    __syncthreads();
    if (tid < 32) {
        const float rsum = rs_part[0][tid] + rs_part[1][tid] +
                           rs_part[2][tid] + rs_part[3][tid];
        inv_rs[tid] = 1.f / rsum;
    }

    __threadfence();
    grid.sync();                          // q0 complete grid-wide; inv_rs ready

    // ---- phase 2: 5 mean-field iterations ----
    const u8* qin = q0;
    u8* qout = q1;
    const int swzr = (r & 7) << 4;

    for (int it = 0; it < 5; ++it) {
        const int lastit = (it == 4);
        const u8* Qb = qin + (size_t)b * DCP * NN + w * 1024;   // wave's k-quarter

#define QSTAGE(c)                                                                   \
        {                                                                           \
            _Pragma("unroll")                                                       \
            for (int i_ = 0; i_ < 8; ++i_) {                                        \
                const int cls_ = 4 * i_ + drow;                                     \
                const u8* gq = Qb + (size_t)cls_ * NN + (c) * 256                   \
                               + (dinn ^ ((cls_ & 7) << 4));                        \
                __builtin_amdgcn_global_load_lds((as1_u32*)gq,                      \
                    (as3_u32*)&bstage[w][(c) & 1][i_ * 1024], 16, 0, 0);            \
            }                                                                       \
        }

        f4v a00 = {0.f,0.f,0.f,0.f}, a01 = {0.f,0.f,0.f,0.f};
        f4v a10 = {0.f,0.f,0.f,0.f}, a11 = {0.f,0.f,0.f,0.f};

        QSTAGE(0);
#pragma unroll
        for (int c = 0; c < 4; ++c) {
            if (c < 3) { QSTAGE(c + 1); WAITVM(8); }
            else       { WAITVM(0); }
            __builtin_amdgcn_sched_barrier(0);
            const char* bufB = &bstage[w][c & 1][0];
#pragma unroll
            for (int ks = 0; ks < 8; ++ks) {
                const int off = ks * 32 + q4 * 8;
                long fbl = *(const long*)&bufB[r        * 256 + (off ^ swzr)];
                long fbh = *(const long*)&bufB[(16 + r) * 256 + (off ^ swzr)];
                const int ki = c * 8 + ks;           // compile-time constant
                a00 = __builtin_amdgcn_mfma_f32_16x16x32_fp8_fp8(dreg[ki],      fbl, a00, 0, 0, 0);
                a01 = __builtin_amdgcn_mfma_f32_16x16x32_fp8_fp8(dreg[ki],      fbh, a01, 0, 0, 0);
                a10 = __builtin_amdgcn_mfma_f32_16x16x32_fp8_fp8(dreg[32 + ki], fbl, a10, 0, 0, 0);
                a11 = __builtin_amdgcn_mfma_f32_16x16x32_fp8_fp8(dreg[32 + ki], fbh, a11, 0, 0, 0);
            }
        }
#undef QSTAGE

        __syncthreads();                 // all waves done reading bstage (Cf alias)
#pragma unroll
        for (int i = 0; i < 4; ++i) {
            Cf[w][0][q4 * 4 + i][r]      = a00[i];
            Cf[w][0][q4 * 4 + i][16 + r] = a01[i];
            Cf[w][1][q4 * 4 + i][r]      = a10[i];
            Cf[w][1][q4 * 4 + i][16 + r] = a11[i];
        }
        __syncthreads();

        // epilogue: thread t -> row16 = t>>4, lg = t&15; two 16-row passes
        const int row16 = tid >> 4;
        const int lg    = tid & 15;
#pragma unroll
        for (int pass = 0; pass < 2; ++pass) {
            const int m = m0 + pass * 16 + row16;
            const float ir = inv_rs[pass * 16 + row16];

            float sd[24];
#pragma unroll
            for (int j = 0; j < 6; ++j) {
                float4 v = make_float4(0.f, 0.f, 0.f, 0.f);
#pragma unroll
                for (int w2 = 0; w2 < 4; ++w2) {
                    float4 cc = *(const float4*)&Cf[w2][pass][row16][j * 4];
                    v.x += cc.x; v.y += cc.y; v.z += cc.z; v.w += cc.w;
                }
                sd[j * 4 + 0] = v.x; sd[j * 4 + 1] = v.y;
                sd[j * 4 + 2] = v.z; sd[j * 4 + 3] = v.w;
            }

            const int d1 = lg;
            const int d2 = 16 + lg;                 // valid iff lg<5
            float u1 = 0.f;
#pragma unroll
            for (int e = 0; e < DC; ++e) u1 += wcs[d1 * DC + e] * sd[e];
            float v1 = seg[((size_t)b * DC + d1) * NN + m] - u1 * ir;

            float v2 = -INFINITY;
            if (lg < 5) {
                float u2 = 0.f;
#pragma unroll
                for (int e = 0; e < DC; ++e) u2 += wcs[d2 * DC + e] * sd[e];
                v2 = seg[((size_t)b * DC + d2) * NN + m] - u2 * ir;
            }

            if (lastit) {
                out[((size_t)b * DC + d1) * NN + m] = v1;
                if (lg < 5) out[((size_t)b * DC + d2) * NN + m] = v2;
            } else {
                float mx = fmaxf(v1, v2);
#pragma unroll
                for (int off = 1; off < 16; off <<= 1) mx = fmaxf(mx, __shfl_xor(mx, off));
                float e1 = __expf(v1 - mx);
                float e2 = (lg < 5) ? __expf(v2 - mx) : 0.f;
                float ss = e1 + e2;
#pragma unroll
                for (int off = 1; off < 16; off <<= 1) ss += __shfl_xor(ss, off);
                float inv = 1.f / ss;
                qnextw(qout, b, d1, m, cvt1(e1 * inv));
                if (lg < 5) qnextw(qout, b, d2, m, cvt1(e2 * inv));
            }
        }

        if (!lastit) {
            __threadfence();
            grid.sync();                 // qout visible; bstage/Cf reuse safe
            const u8* t = qin; qin = qout; qout = (u8*)t;
        }
    }
}

// ==================== round-2 fallback kernels ====================
__global__ __launch_bounds__(64) void prep_k(const float* __restrict__ W,
                                             u8* __restrict__ D) {
    const int m = blockIdx.x;
    const int l = threadIdx.x;
    const float4* Wr = (const float4*)(W + (size_t)m * NN) + l;
    float4 v[16];
    float s = 0.f;
#pragma unroll
    for (int i = 0; i < 16; ++i) {
        v[i] = Wr[i * 64];
        s += (v[i].x + v[i].y) + (v[i].z + v[i].w);
    }
#pragma unroll
    for (int off = 1; off < 64; off <<= 1) s += __shfl_xor(s, off);
    const float inv2k = 2048.f / s;
    u32* Dr = (u32*)(D + (size_t)m * NN);
#pragma unroll
    for (int i = 0; i < 16; ++i) {
        Dr[i * 64 + l] = cvtpk4(v[i].x * inv2k, v[i].y * inv2k,
                                v[i].z * inv2k, v[i].w * inv2k);
    }
}

__global__ __launch_bounds__(256) void softmax0_k(const float* __restrict__ x,
                                                  u8* __restrict__ q) {
    unsigned gid = blockIdx.x * 256u + threadIdx.x;
    unsigned b = gid >> 12, n = gid & 4095u;
    const float* xb = x + (size_t)b * DC * NN + n;
    float v[DC];
    float m = -1e30f;
#pragma unroll
    for (int d = 0; d < DC; ++d) { v[d] = xb[(size_t)d * NN]; m = fmaxf(m, v[d]); }
    float s = 0.f;
#pragma unroll
    for (int d = 0; d < DC; ++d) { v[d] = __expf(v[d] - m); s += v[d]; }
    float inv = 1.f / s;
    u8* qb = q + (size_t)b * DCP * NN + n;
#pragma unroll
    for (int d = 0; d < DC; ++d) qb[(size_t)d * NN] = cvt1(v[d] * inv);
}

__global__ __launch_bounds__(256, 2) void iter_k(const u8* __restrict__ Q,
                                                 const u8* __restrict__ D,
                                                 const float* __restrict__ wc,
                                                 const float* __restrict__ seg,
                                                 u8* __restrict__ qnext,
                                                 float* __restrict__ out,
                                                 int last) {
    __shared__ __align__(16) char lds[4][16384];
    __shared__ float wcs[DC * DC];
    float (*Cf)[2][16][DCP] = (float (*)[2][16][DCP])&lds[0][0];

    const int tid = threadIdx.x;
    const int w   = tid >> 6;
    const int l   = tid & 63;
    const int b   = blockIdx.x >> 7;
    const int m0  = (blockIdx.x & 127) * 32;

    for (int i = tid; i < DC * DC; i += 256)
        wcs[i] = wc[i] * (1.f / 2048.f);

    const int r  = l & 15;
    const int q4 = l >> 4;

    const u8* Db = D + ((size_t)b * NN + m0) * NN;
    const u8* Qb = Q + (size_t)b * DCP * NN;

    const int drow = l >> 4;
    const int dinn = (l & 15) * 16;

    f4v a00 = {0.f,0.f,0.f,0.f}, a01 = {0.f,0.f,0.f,0.f};
    f4v a10 = {0.f,0.f,0.f,0.f}, a11 = {0.f,0.f,0.f,0.f};

#define STAGE(c)                                                                     \
    {                                                                                \
        const int bi_ = (c) & 3;                                                     \
        _Pragma("unroll")                                                            \
        for (int ii = 0; ii < 2; ++ii) {                                             \
            const int i_   = w * 2 + ii;                                             \
            const int row_ = 4 * i_ + drow;                                          \
            const u8* ga = Db + (size_t)row_ * NN + (c) * 256                        \
                           + (dinn ^ ((row_ & 7) << 4));                             \
            __builtin_amdgcn_global_load_lds((as1_u32*)ga,                           \
                (as3_u32*)&lds[bi_][i_ * 1024], 16, 0, 0);                           \
            const u8* gb = Qb + (size_t)row_ * NN + (c) * 256                        \
                           + (dinn ^ ((row_ & 7) << 4));                             \
            __builtin_amdgcn_global_load_lds((as1_u32*)gb,                           \
                (as3_u32*)&lds[bi_][8192 + i_ * 1024], 16, 0, 0);                    \
        }                                                                            \
    }

    STAGE(0);
    STAGE(1);
    STAGE(2);

    const int swzr  = (r & 7) << 4;
    const int kbase = w * 64 + q4 * 8;

#pragma unroll
    for (int c = 0; c < 16; ++c) {
        if (c < 14) { WAITVM(8); }
        else if (c == 14) { WAITVM(4); }
        else { WAITVM(0); }
        __builtin_amdgcn_s_barrier();
        __builtin_amdgcn_sched_barrier(0);
        if (c + 3 < 16) STAGE(c + 3);

        const char* bufA = &lds[c & 3][0];
        const char* bufB = &lds[c & 3][8192];
#pragma unroll
        for (int ks = 0; ks < 2; ++ks) {
            const int off = kbase + ks * 32;
            long fa0 = *(const long*)&bufA[(r)      * 256 + (off ^ swzr)];
            long fa1 = *(const long*)&bufA[(16 + r) * 256 + (off ^ swzr)];
            long fbl = *(const long*)&bufB[(r)      * 256 + (off ^ swzr)];
            long fbh = *(const long*)&bufB[(16 + r) * 256 + (off ^ swzr)];
            a00 = __builtin_amdgcn_mfma_f32_16x16x32_fp8_fp8(fa0, fbl, a00, 0, 0, 0);
            a01 = __builtin_amdgcn_mfma_f32_16x16x32_fp8_fp8(fa0, fbh, a01, 0, 0, 0);
            a10 = __builtin_amdgcn_mfma_f32_16x16x32_fp8_fp8(fa1, fbl, a10, 0, 0, 0);
            a11 = __builtin_amdgcn_mfma_f32_16x16x32_fp8_fp8(fa1, fbh, a11, 0, 0, 0);
        }
    }
#undef STAGE

#pragma unroll
    for (int i = 0; i < 4; ++i) {
        Cf[w][0][q4 * 4 + i][r]      = a00[i];
        Cf[w][0][q4 * 4 + i][16 + r] = a01[i];
        Cf[w][1][q4 * 4 + i][r]      = a10[i];
        Cf[w][1][q4 * 4 + i][16 + r] = a11[i];
    }
    __syncthreads();

    const int row16 = tid >> 4;
    const int lg    = tid & 15;
#pragma unroll
    for (int pass = 0; pass < 2; ++pass) {
        const int m = m0 + pass * 16 + row16;

        float sd[24];
#pragma unroll
        for (int j = 0; j < 6; ++j) {
            float4 v = make_float4(0.f, 0.f, 0.f, 0.f);
#pragma unroll
            for (int w2 = 0; w2 < 4; ++w2) {
                float4 cc = *(const float4*)&Cf[w2][pass][row16][j * 4];
                v.x += cc.x; v.y += cc.y; v.z += cc.z; v.w += cc.w;
            }
            sd[j * 4 + 0] = v.x; sd[j * 4 + 1] = v.y;
            sd[j * 4 + 2] = v.z; sd[j * 4 + 3] = v.w;
        }

        const int d1 = lg;
        const int d2 = 16 + lg;
        float u1 = 0.f;
#pragma unroll
        for (int e = 0; e < DC; ++e) u1 += wcs[d1 * DC + e] * sd[e];
        float v1 = seg[((size_t)b * DC + d1) * NN + m] - u1;

        float v2 = -INFINITY;
        if (lg < 5) {
            float u2 = 0.f;
#pragma unroll
            for (int e = 0; e < DC; ++e) u2 += wcs[d2 * DC + e] * sd[e];
            v2 = seg[((size_t)b * DC + d2) * NN + m] - u2;
        }

        if (last) {
            out[((size_t)b * DC + d1) * NN + m] = v1;
            if (lg < 5) out[((size_t)b * DC + d2) * NN + m] = v2;
        } else {
            float mx = fmaxf(v1, v2);
#pragma unroll
            for (int off = 1; off < 16; off <<= 1) mx = fmaxf(mx, __shfl_xor(mx, off));
            float e1 = __expf(v1 - mx);
            float e2 = (lg < 5) ? __expf(v2 - mx) : 0.f;
            float ss = e1 + e2;
#pragma unroll
            for (int off = 1; off < 16; off <<= 1) ss += __shfl_xor(ss, off);
            float inv = 1.f / ss;
            qnext[((size_t)b * DCP + d1) * NN + m] = cvt1(e1 * inv);
            if (lg < 5) qnext[((size_t)b * DCP + d2) * NN + m] = cvt1(e2 * inv);
        }
    }
}

// ======== fp32 fallback (round-2 structure) if ws too small ========
__global__ __launch_bounds__(256) void fb_softmax_k(const float* __restrict__ x,
                                                    float* __restrict__ q) {
    unsigned gid = blockIdx.x * 256u + threadIdx.x;
    unsigned b = gid >> 12, n = gid & 4095u;
    const float* xb = x + (size_t)b * DC * NN + n;
    float v[DC]; float m = -1e30f;
#pragma unroll
    for (int d = 0; d < DC; ++d) { v[d] = xb[(size_t)d * NN]; m = fmaxf(m, v[d]); }
    float s = 0.f;
#pragma unroll
    for (int d = 0; d < DC; ++d) { v[d] = __expf(v[d] - m); s += v[d]; }
    float inv = 1.f / s;
    float* qb = q + (size_t)b * DC * NN + n;
#pragma unroll
    for (int d = 0; d < DC; ++d) qb[(size_t)d * NN] = v[d] * inv;
}

__global__ __launch_bounds__(64) void fb_iter_k(const float* __restrict__ Q,
                                                const float* __restrict__ W,
                                                const float* __restrict__ wc,
                                                const float* __restrict__ seg,
                                                float* __restrict__ qnext,
                                                float* __restrict__ out,
                                                int write_q, int write_out) {
    const int lane = threadIdx.x;
    const int g = lane >> 4, l = lane & 15;
    const int b = blockIdx.x >> 9, rb = blockIdx.x & 511;
    const int m0 = rb * 8 + g * 2;
    const float4* Wr0 = (const float4*)(W + ((size_t)b * NN + m0) * NN + l * 4);
    const float4* Wr1 = (const float4*)(W + ((size_t)b * NN + m0 + 1) * NN + l * 4);
    const float4* Qf4 = (const float4*)(Q + (size_t)b * DC * NN + l * 4);
    float acc0[DC], acc1[DC];
#pragma unroll
    for (int d = 0; d < DC; ++d) { acc0[d] = 0.f; acc1[d] = 0.f; }
    float rs0 = 0.f, rs1 = 0.f;
#pragma unroll 2
    for (int s = 0; s < 64; ++s) {
        float4 wa = Wr0[s * 16], wb = Wr1[s * 16];
        rs0 += (wa.x + wa.y) + (wa.z + wa.w);
        rs1 += (wb.x + wb.y) + (wb.z + wb.w);
#pragma unroll
        for (int d = 0; d < DC; ++d) {
            float4 qv = Qf4[d * 1024 + s * 16];
            acc0[d] += qv.x * wa.x + qv.y * wa.y + qv.z * wa.z + qv.w * wa.w;
            acc1[d] += qv.x * wb.x + qv.y * wb.y + qv.z * wb.z + qv.w * wb.w;
        }
    }
#pragma unroll
    for (int off = 1; off < 16; off <<= 1) {
        rs0 += __shfl_xor(rs0, off); rs1 += __shfl_xor(rs1, off);
#pragma unroll
        for (int d = 0; d < DC; ++d) {
            acc0[d] += __shfl_xor(acc0[d], off);
            acc1[d] += __shfl_xor(acc1[d], off);
        }
    }
    const float inv0 = 1.f / rs0, inv1 = 1.f / rs1;
    const int d1 = l, d2 = l + 16;
    const bool has2 = (d2 < DC);
    float u0a = 0.f, u1a = 0.f, u0b = 0.f, u1b = 0.f;
#pragma unroll
    for (int e = 0; e < DC; ++e) {
        float w1 = wc[d1 * DC + e];
        u0a += w1 * acc0[e]; u1a += w1 * acc1[e];
    }
    if (has2) {
#pragma unroll
        for (int e = 0; e < DC; ++e) {
            float w2 = wc[d2 * DC + e];
            u0b += w2 * acc0[e]; u1b += w2 * acc1[e];
        }
    }
    const size_t base = (size_t)b * DC * NN;
    const size_t i0a = base + (size_t)d1 * NN + m0;
    const size_t i0b = base + (size_t)d2 * NN + m0;
    float v0a = seg[i0a] - u0a * inv0;
    float v1a = seg[i0a + 1] - u1a * inv1;
    float v0b = 0.f, v1b = 0.f;
    if (has2) { v0b = seg[i0b] - u0b * inv0; v1b = seg[i0b + 1] - u1b * inv1; }
    if (write_out) {
        out[i0a] = v0a; out[i0a + 1] = v1a;
        if (has2) { out[i0b] = v0b; out[i0b + 1] = v1b; }
    }
    if (write_q) {
        float mx0 = has2 ? fmaxf(v0a, v0b) : v0a;
        float mx1 = has2 ? fmaxf(v1a, v1b) : v1a;
#pragma unroll
        for (int off = 1; off < 16; off <<= 1) {
            mx0 = fmaxf(mx0, __shfl_xor(mx0, off));
            mx1 = fmaxf(mx1, __shfl_xor(mx1, off));
        }
        float e0a = __expf(v0a - mx0), e1a = __expf(v1a - mx1);
        float e0b = has2 ? __expf(v0b - mx0) : 0.f;
        float e1b = has2 ? __expf(v1b - mx1) : 0.f;
        float s0 = e0a + e0b, s1 = e1a + e1b;
#pragma unroll
        for (int off = 1; off < 16; off <<= 1) {
            s0 += __shfl_xor(s0, off); s1 += __shfl_xor(s1, off);
        }
        float is0 = 1.f / s0, is1 = 1.f / s1;
        qnext[i0a] = e0a * is0; qnext[i0a + 1] = e1a * is1;
        if (has2) { qnext[i0b] = e0b * is0; qnext[i0b + 1] = e1b * is1; }
    }
}

extern "C" void kernel_launch(void* const* d_in, const int* in_sizes, int n_in,
                              void* d_out, int out_size, void* d_ws, size_t ws_size,
                              hipStream_t stream) {
    const float* seg = (const float*)d_in[0];
    const float* W   = (const float*)d_in[1];
    const float* wc  = (const float*)d_in[2];
    float* out = (float*)d_out;

    const size_t needD = (size_t)BS * NN * NN * sizeof(u8);       // 67,108,864
    const size_t needQ = (size_t)BS * DCP * NN * sizeof(u8);      // 524,288

    bool done = false;

    // ---- preferred: one persistent cooperative kernel ----
    if (ws_size >= needQ && (size_t)out_size * sizeof(float) >= needQ) {
        u8* q0 = (u8*)d_ws;
        u8* q1 = (u8*)d_out;
        void* args[6] = {(void*)&seg, (void*)&W, (void*)&wc,
                         (void*)&q0, (void*)&q1, (void*)&out};
        hipError_t e = hipLaunchCooperativeKernel((const void*)fused_k,
                                                  dim3(512), dim3(256),
                                                  args, 0, stream);
        done = (e == hipSuccess);
    }

    // ---- fallback: round-2 multi-kernel path ----
    if (!done && ws_size >= needD + needQ &&
        (size_t)out_size * sizeof(float) >= needQ) {
        u8* Dq = (u8*)d_ws;
        u8* Q0 = (u8*)((char*)d_ws + needD);
        u8* Q1 = (u8*)d_out;

        prep_k<<<dim3(BS * NN), dim3(64), 0, stream>>>(W, Dq);
        softmax0_k<<<dim3(BS * NN / 256), dim3(256), 0, stream>>>(seg, Q0);

        const u8* qin = Q0;
        u8* qout = Q1;
        for (int it = 0; it < 5; ++it) {
            iter_k<<<dim3(BS * NN / 32), dim3(256), 0, stream>>>(
                qin, Dq, wc, seg, qout, out, (it == 4) ? 1 : 0);
            const u8* t = qin; qin = qout; qout = (u8*)t;
        }
        done = true;
    }

    // ---- last-resort fp32 path ----
    if (!done) {
        float* Qa = (float*)d_ws;
        float* Qb = Qa + (size_t)BS * DC * NN;
        fb_softmax_k<<<dim3(BS * NN / 256), dim3(256), 0, stream>>>(seg, Qa);
        const float* qin = Qa;
        float* qout = Qb;
        for (int it = 0; it < 5; ++it) {
            fb_iter_k<<<dim3(2048), dim3(64), 0, stream>>>(
                qin, W, wc, seg, qout, out, (it < 4) ? 1 : 0, (it == 4) ? 1 : 0);
            const float* t = qin; qin = qout; qout = (float*)t;
        }
    }
}